// Round 7
// baseline (2098.787 us; speedup 1.0000x reference)
//
#include <hip/hip_runtime.h>

#define NN    9216      /* 96*96   */
#define MM    2304      /* 48*48   */
#define HW    36864     /* 192*192 */
#define SLABF 4718592   /* f32 per batch slab of output: 128*192*192 */
#define TEMPF 5.0f

/* d_out f32 offsets (scratch; lifetimes verified):
   x    [0        , 4718592)   dead after theta/phi convs
   y    [4718592  , 9437184)   dead after g conv
   th   [9437184  , 11796480)  dead after attn
   tp   [11796480 , 14155776)  pre-pool temp, dead after pools
   ph   [14155776 , 14745600)  dead after attn
   g    [14745600 , 15335424)  dead after attn
   omap [15335424 , 17694720)  attn out, read by oconv
   ofin : swizzled into plane-0..31 prefix of each batch slab
          [b*SLABF, b*SLABF+1179648)  (regions dead at oconv time)
          k_up block (b,i) reads ONLY rows 2i,2i+1 of planes 0..31 of slab b
          = inside its own exclusive write region -> race-free in-place. */
#define OFF_X   0
#define OFF_Y   4718592
#define OFF_TH  9437184
#define OFF_TP  11796480
#define OFF_PH  14155776
#define OFF_G   14745600
#define OFF_OM  15335424

/* ---- down conv k=2 s=2, 128->128, all f32 ---- */
__global__ __launch_bounds__(256) void k_down(const float* __restrict__ in,
    const float* __restrict__ w, const float* __restrict__ bias, float* __restrict__ out)
{
  int t = blockIdx.x*256 + threadIdx.x;     /* (b, i, o, jg) jg fastest */
  int jg = t % 24; int r = t / 24;
  int o  = r % 128; r /= 128;
  int i  = r % 96;  int b = r / 96;
  int j0 = jg*4;
  const float* ip = in + (size_t)b*128*HW + (size_t)(2*i)*192 + 2*j0;
  const float* wp = w + (size_t)o*512;
  float bv = bias[o];
  float a0=bv, a1=bv, a2=bv, a3=bv;
  for (int c = 0; c < 128; c++) {
    const float* p = ip + (size_t)c*HW;
    float4 r0a = *(const float4*)p;
    float4 r0b = *(const float4*)(p + 4);
    float4 r1a = *(const float4*)(p + 192);
    float4 r1b = *(const float4*)(p + 196);
    float4 wv  = *(const float4*)(wp + c*4);   /* w00 w01 w10 w11 */
    a0 += r0a.x*wv.x + r0a.y*wv.y + r1a.x*wv.z + r1a.y*wv.w;
    a1 += r0a.z*wv.x + r0a.w*wv.y + r1a.z*wv.z + r1a.w*wv.w;
    a2 += r0b.x*wv.x + r0b.y*wv.y + r1b.x*wv.z + r1b.y*wv.w;
    a3 += r0b.z*wv.x + r0b.w*wv.y + r1b.z*wv.z + r1b.w*wv.w;
  }
  float* op = out + ((size_t)(b*128 + o))*NN + i*96 + j0;
  *(float4*)op = make_float4(a0,a1,a2,a3);
}

/* ---- 1x1 conv 128->64: out[b][cc][n] = sum_c W[cc][c]*X[b][c][n] ---- */
__global__ __launch_bounds__(256) void k_conv(const float* __restrict__ X,
    const float* __restrict__ WG, float* __restrict__ out)
{
  __shared__ __align__(16) float Xs[128*32];   /* [c][32 n] 16KB */
  __shared__ __align__(16) float wt[128*64];   /* [c][cc]   32KB */
  int b  = blockIdx.x / 288;
  int n0 = (blockIdx.x % 288) * 32;
  int t  = threadIdx.x;
  for (int idx = t; idx < 8192; idx += 256) {
    int c = idx >> 6, cc = idx & 63;
    wt[idx] = WG[cc*128 + c];
  }
  for (int idx = t; idx < 1024; idx += 256) {  /* 128 rows x 8 float4 */
    int c = idx >> 3, wq = idx & 7;
    ((float4*)Xs)[idx] = *(const float4*)&X[((size_t)(b*128 + c))*NN + n0 + wq*4];
  }
  __syncthreads();
  int n = t & 31, og = t >> 5;      /* og 0..7 -> cc = og*8+k */
  float acc[8];
  #pragma unroll
  for (int k = 0; k < 8; k++) acc[k] = 0.f;
  for (int c = 0; c < 128; c++) {
    float xv = Xs[(c<<5) + n];
    const float* wrow = wt + (c<<6) + og*8;
    float4 wa = *(const float4*)wrow;
    float4 wb = *(const float4*)(wrow + 4);
    acc[0]+=wa.x*xv; acc[1]+=wa.y*xv; acc[2]+=wa.z*xv; acc[3]+=wa.w*xv;
    acc[4]+=wb.x*xv; acc[5]+=wb.y*xv; acc[6]+=wb.z*xv; acc[7]+=wb.w*xv;
  }
  #pragma unroll
  for (int k = 0; k < 8; k++)
    out[((size_t)(b*64 + og*8 + k))*NN + n0 + n] = acc[k];
}

/* ---- 2x2 maxpool f32 [b][64][96][96] -> [b][64][48][48] ---- */
__global__ __launch_bounds__(256) void k_pool(const float* __restrict__ in, float* __restrict__ out)
{
  int t = blockIdx.x*256 + threadIdx.x;   /* 589824 */
  int J = t % 48; int r = t/48; int I = r % 48; r /= 48; int cc = r & 63; int b = r >> 6;
  const float* p = in + ((size_t)(b*64+cc))*NN + (size_t)(2*I)*96 + 2*J;
  float m = fmaxf(fmaxf(p[0],p[1]), fmaxf(p[96],p[97]));
  out[((size_t)(b*64+cc))*MM + I*48 + J] = m;
}

/* ---- flash attention: 32-query tile per block, 64-key chunks (all f32) ---- */
__global__ __launch_bounds__(256) void k_attn(const float* __restrict__ TH,
    const float* __restrict__ PH, const float* __restrict__ G, float* __restrict__ OUT)
{
  __shared__ __align__(16) float th[64*32];    /* [c][q]  8KB  */
  __shared__ __align__(16) float ph[64*64];    /* [c][k] 16KB  */
  __shared__ __align__(16) float gs[64*64];    /* [c][k] 16KB  */
  __shared__ __align__(16) float S [64*33];    /* [k][q] 8.25KB */
  __shared__ float mrow[32], lrow[32], arow[32];
  int t  = threadIdx.x;
  int b  = blockIdx.x / 288;
  int q0 = (blockIdx.x % 288) * 32;
  for (int idx = t; idx < 2048; idx += 256)
    th[idx] = TH[((size_t)(b*64 + (idx>>5)))*NN + q0 + (idx&31)];
  if (t < 32) { mrow[t] = -3.0e38f; lrow[t] = 0.f; }
  float acc[8] = {0,0,0,0,0,0,0,0};
  int q  = t & 31;
  int g8 = t >> 5;           /* 0..7 */
  __syncthreads();
  for (int k0 = 0; k0 < MM; k0 += 64) {
    for (int idx = t; idx < 4096; idx += 256) {
      size_t src = ((size_t)(b*64 + (idx>>6)))*MM + k0 + (idx&63);
      ph[idx] = PH[src];
      gs[idx] = G[src];
    }
    __syncthreads();
    { /* QK^T: thread -> (q, k = g8*8 .. +7) */
      float s0=0,s1=0,s2=0,s3=0,s4=0,s5=0,s6=0,s7=0;
      #pragma unroll 4
      for (int c = 0; c < 64; c++) {
        float tv = th[(c<<5) + q];
        const float* pr = &ph[(c<<6) + (g8<<3)];
        float4 pa = *(const float4*)pr;
        float4 pb = *(const float4*)(pr+4);
        s0 += tv*pa.x; s1 += tv*pa.y; s2 += tv*pa.z; s3 += tv*pa.w;
        s4 += tv*pb.x; s5 += tv*pb.y; s6 += tv*pb.z; s7 += tv*pb.w;
      }
      int kb = g8<<3;
      S[(kb+0)*33+q] = TEMPF*s0; S[(kb+1)*33+q] = TEMPF*s1;
      S[(kb+2)*33+q] = TEMPF*s2; S[(kb+3)*33+q] = TEMPF*s3;
      S[(kb+4)*33+q] = TEMPF*s4; S[(kb+5)*33+q] = TEMPF*s5;
      S[(kb+6)*33+q] = TEMPF*s6; S[(kb+7)*33+q] = TEMPF*s7;
    }
    __syncthreads();
    if (t < 32) { /* online softmax, one row per thread */
      float mo = mrow[t];
      float mx = mo;
      for (int k = 0; k < 64; k++) mx = fmaxf(mx, S[k*33+t]);
      float alpha = __expf(mo - mx);
      float ls = 0.f;
      for (int k = 0; k < 64; k++) {
        float p = __expf(S[k*33+t] - mx);
        S[k*33+t] = p; ls += p;
      }
      mrow[t] = mx;
      lrow[t] = lrow[t]*alpha + ls;
      arow[t] = alpha;
    }
    __syncthreads();
    { /* PV: thread -> (q, c = g8*8 .. +7) */
      float al = arow[q];
      #pragma unroll
      for (int cc = 0; cc < 8; cc++) acc[cc] *= al;
      #pragma unroll 4
      for (int k4 = 0; k4 < 16; k4++) {
        float p0 = S[(k4*4+0)*33+q];
        float p1 = S[(k4*4+1)*33+q];
        float p2 = S[(k4*4+2)*33+q];
        float p3 = S[(k4*4+3)*33+q];
        #pragma unroll
        for (int cc = 0; cc < 8; cc++) {
          const float4 gv = *(const float4*)&gs[((g8*8+cc)<<6) + (k4<<2)];
          acc[cc] += gv.x*p0 + gv.y*p1 + gv.z*p2 + gv.w*p3;
        }
      }
    }
    __syncthreads();
  }
  float li = 1.0f / lrow[q];
  #pragma unroll
  for (int cc = 0; cc < 8; cc++)
    OUT[((size_t)(b*64 + g8*8+cc))*NN + q0 + q] = acc[cc]*li;
}

/* ---- o-projection 64->128, swizzled store into k_up block-own prefixes:
   ofin[b][o][i][j] -> dout[b slab][plane o>>2][2i+((o>>1)&1)][2j+(o&1)] ---- */
__global__ __launch_bounds__(256) void k_oconv(const float* __restrict__ X,
    const float* __restrict__ OW, float* __restrict__ dout)
{
  __shared__ __align__(16) float Xs[64*64];    /* [cc][64 n] 16KB */
  __shared__ __align__(16) float wt[64*128];   /* [cc][o]    32KB */
  int b  = blockIdx.x / 144;
  int n0 = (blockIdx.x % 144) * 64;
  int t  = threadIdx.x;
  for (int idx = t; idx < 8192; idx += 256) {
    int cc = idx >> 7, o = idx & 127;
    wt[idx] = OW[o*64 + cc];
  }
  for (int idx = t; idx < 1024; idx += 256) {  /* 64 rows x 16 float4 */
    int cc = idx >> 4, wq = idx & 15;
    ((float4*)Xs)[idx] = *(const float4*)&X[((size_t)(b*64 + cc))*NN + n0 + wq*4];
  }
  __syncthreads();
  int n = t & 63, og = t >> 6;       /* og 0..3 -> o = og*32+k */
  float acc[32];
  #pragma unroll
  for (int k = 0; k < 32; k++) acc[k] = 0.f;
  for (int cc = 0; cc < 64; cc++) {
    float xv = Xs[(cc << 6) + n];
    const float* wrow = wt + (cc << 7) + og*32;
    #pragma unroll
    for (int k = 0; k < 32; k++) acc[k] += wrow[k]*xv;
  }
  int ng = n0 + n;
  int i = ng / 96, j = ng - (ng/96)*96;
  #pragma unroll
  for (int k = 0; k < 32; k++) {
    int o = og*32 + k;
    size_t addr = (size_t)b*SLABF + (size_t)(o>>2)*HW
                + (size_t)(2*i + ((o>>1)&1))*192 + 2*j + (o&1);
    dout[addr] = acc[k];
  }
}

/* ---- up convtranspose + bias + gamma*y, f32, in-place over d_out.
   Block (b,i): phase 0 loads its own swizzled prefix rows (planes 0..31,
   rows 2i..2i+1) into LDS, syncs, then computes/writes rows 2i..2i+1 of
   all 128 planes. Reads outside LDS: only y_in/upw/upb (inputs). ---- */
__global__ __launch_bounds__(256) void k_up(float* __restrict__ dout,
    const float* __restrict__ upw, const float* __restrict__ upb,
    const float* __restrict__ Y, const float* __restrict__ gamma_p)
{
  __shared__ __align__(16) float o_s[128*96];   /* [c][j] 48KB */
  int blk = blockIdx.x;
  int b = blk / 96, i = blk - b*96;
  int t = threadIdx.x;
  size_t slab = (size_t)b*SLABF;
  const float* src = dout + slab + (size_t)(2*i)*192;

  /* phase 0: unswizzle own prefix -> LDS */
  for (int idx = t; idx < 12288; idx += 256) {   /* 32 planes x 2 rows x 192 */
    int run = idx / 384, rem = idx - run*384;
    int r = rem / 192, col = rem - r*192;
    float v = src[(size_t)run*HW + r*192 + col];
    int o = 4*run + 2*r + (col&1);
    o_s[o*96 + (col>>1)] = v;
  }
  __syncthreads();

  int op5 = t >> 3, jg = t & 7;
  float gm = *gamma_p;

  for (int opc = 0; opc < 4; opc++) {
    int op = opc*32 + op5;
    float bias = upb[op];
    size_t obase = slab + (size_t)op*HW + (size_t)(2*i)*192;
    for (int s = 0; s < 3; s++) {
      int j0 = jg*12 + s*4;
      float a00[4], a01[4], a10[4], a11[4];
      #pragma unroll
      for (int jj = 0; jj < 4; jj++) { a00[jj]=0.f; a01[jj]=0.f; a10[jj]=0.f; a11[jj]=0.f; }
      for (int c = 0; c < 128; c++) {
        float4 ov = *(const float4*)&o_s[c*96 + j0];
        float4 wv = *(const float4*)&upw[((size_t)c*128 + op)*4];  /* w00 w01 w10 w11 */
        a00[0]+=ov.x*wv.x; a01[0]+=ov.x*wv.y; a10[0]+=ov.x*wv.z; a11[0]+=ov.x*wv.w;
        a00[1]+=ov.y*wv.x; a01[1]+=ov.y*wv.y; a10[1]+=ov.y*wv.z; a11[1]+=ov.y*wv.w;
        a00[2]+=ov.z*wv.x; a01[2]+=ov.z*wv.y; a10[2]+=ov.z*wv.z; a11[2]+=ov.z*wv.w;
        a00[3]+=ov.w*wv.x; a01[3]+=ov.w*wv.y; a10[3]+=ov.w*wv.z; a11[3]+=ov.w*wv.w;
      }
      size_t p0 = obase + 2*j0;          /* row 2i,  col 2*j0 */
      size_t p1 = p0 + 192;              /* row 2i+1 */
      float4 y0a = *(const float4*)&Y[p0];
      float4 y0b = *(const float4*)&Y[p0 + 4];
      float4 y1a = *(const float4*)&Y[p1];
      float4 y1b = *(const float4*)&Y[p1 + 4];
      *(float4*)&dout[p0]     = make_float4(a00[0]+bias+gm*y0a.x, a01[0]+bias+gm*y0a.y,
                                            a00[1]+bias+gm*y0a.z, a01[1]+bias+gm*y0a.w);
      *(float4*)&dout[p0 + 4] = make_float4(a00[2]+bias+gm*y0b.x, a01[2]+bias+gm*y0b.y,
                                            a00[3]+bias+gm*y0b.z, a01[3]+bias+gm*y0b.w);
      *(float4*)&dout[p1]     = make_float4(a10[0]+bias+gm*y1a.x, a11[0]+bias+gm*y1a.y,
                                            a10[1]+bias+gm*y1a.z, a11[1]+bias+gm*y1a.w);
      *(float4*)&dout[p1 + 4] = make_float4(a10[2]+bias+gm*y1b.x, a11[2]+bias+gm*y1b.y,
                                            a10[3]+bias+gm*y1b.z, a11[3]+bias+gm*y1b.w);
    }
  }
}

extern "C" void kernel_launch(void* const* d_in, const int* in_sizes, int n_in,
                              void* d_out, int out_size, void* d_ws, size_t ws_size,
                              hipStream_t stream) {
  const float* x_in  = (const float*)d_in[0];
  const float* y_in  = (const float*)d_in[1];
  const float* d0w   = (const float*)d_in[2];
  const float* d0b   = (const float*)d_in[3];
  const float* d1w   = (const float*)d_in[4];
  const float* d1b   = (const float*)d_in[5];
  const float* thw   = (const float*)d_in[6];
  const float* phw   = (const float*)d_in[7];
  const float* gw    = (const float*)d_in[8];
  const float* ow    = (const float*)d_in[9];
  const float* upw   = (const float*)d_in[10];
  const float* upb   = (const float*)d_in[11];
  const float* gamma = (const float*)d_in[12];
  float* out = (float*)d_out;

  /* d_ws UNUSED; d_in READ-ONLY; all scratch in d_out (see offset map). */
  k_down <<<4608, 256, 0, stream>>>(x_in, d0w, d0b, out + OFF_X);
  k_down <<<4608, 256, 0, stream>>>(y_in, d1w, d1b, out + OFF_Y);
  k_conv <<<1152, 256, 0, stream>>>(out + OFF_X, thw, out + OFF_TH);
  k_conv <<<1152, 256, 0, stream>>>(out + OFF_X, phw, out + OFF_TP);
  k_pool <<<2304, 256, 0, stream>>>(out + OFF_TP, out + OFF_PH);
  k_conv <<<1152, 256, 0, stream>>>(out + OFF_Y, gw, out + OFF_TP);
  k_pool <<<2304, 256, 0, stream>>>(out + OFF_TP, out + OFF_G);
  k_attn <<<1152, 256, 0, stream>>>(out + OFF_TH, out + OFF_PH, out + OFF_G, out + OFF_OM);
  k_oconv<<<576,  256, 0, stream>>>(out + OFF_OM, ow, out);
  k_up   <<<384,  256, 0, stream>>>(out, upw, upb, y_in, gamma);
}

// Round 8
// 1249.610 us; speedup vs baseline: 1.6796x; 1.6796x over previous
//
#include <hip/hip_runtime.h>
#include <hip/hip_bf16.h>

#define NN    9216      /* 96*96   */
#define MM    2304      /* 48*48   */
#define HW    36864     /* 192*192 */
#define SLABF 4718592   /* f32 per batch slab of output: 128*192*192 */
#define TEMPF 5.0f

/* d_out f32 offsets (scratch; lifetimes verified):
   x    [0        , 4718592)   dead after theta/phi convs
   y    [4718592  , 9437184)   dead after g conv
   th   [9437184  , 11796480)  dead after attn
   tp   [11796480 , 14155776)  pre-pool temp, dead after pools
   ph   [14155776 , 14745600)  dead after attn
   g    [14745600 , 15335424)  dead after attn
   omap [15335424 , 17694720)  attn out, read by oconv
   ofin : swizzled into plane-0..31 prefix of each batch slab (race-free k_up) */
#define OFF_X   0
#define OFF_Y   4718592
#define OFF_TH  9437184
#define OFF_TP  11796480
#define OFF_PH  14155776
#define OFF_G   14745600
#define OFF_OM  15335424

typedef unsigned short u16;
typedef unsigned int   u32;
typedef __attribute__((ext_vector_type(8))) short bf16x8;
typedef __attribute__((ext_vector_type(4))) float f32x4;

__device__ __forceinline__ u16 f2bf(float f){
  u32 u; __builtin_memcpy(&u,&f,4);
  u32 lsb = (u>>16)&1u; u += 0x7fffu + lsb;   /* RNE */
  return (u16)(u>>16);
}
__device__ __forceinline__ u32 pkbf(float a, float b){
  union { __hip_bfloat162 h; u32 u; } v;
  v.h = __float22bfloat162_rn(make_float2(a,b));
  return v.u;
}

/* ---- down conv k=2 s=2, 128->128, all f32 ---- */
__global__ __launch_bounds__(256) void k_down(const float* __restrict__ in,
    const float* __restrict__ w, const float* __restrict__ bias, float* __restrict__ out)
{
  int t = blockIdx.x*256 + threadIdx.x;     /* (b, i, o, jg) jg fastest */
  int jg = t % 24; int r = t / 24;
  int o  = r % 128; r /= 128;
  int i  = r % 96;  int b = r / 96;
  int j0 = jg*4;
  const float* ip = in + (size_t)b*128*HW + (size_t)(2*i)*192 + 2*j0;
  const float* wp = w + (size_t)o*512;
  float bv = bias[o];
  float a0=bv, a1=bv, a2=bv, a3=bv;
  for (int c = 0; c < 128; c++) {
    const float* p = ip + (size_t)c*HW;
    float4 r0a = *(const float4*)p;
    float4 r0b = *(const float4*)(p + 4);
    float4 r1a = *(const float4*)(p + 192);
    float4 r1b = *(const float4*)(p + 196);
    float4 wv  = *(const float4*)(wp + c*4);   /* w00 w01 w10 w11 */
    a0 += r0a.x*wv.x + r0a.y*wv.y + r1a.x*wv.z + r1a.y*wv.w;
    a1 += r0a.z*wv.x + r0a.w*wv.y + r1a.z*wv.z + r1a.w*wv.w;
    a2 += r0b.x*wv.x + r0b.y*wv.y + r1b.x*wv.z + r1b.y*wv.w;
    a3 += r0b.z*wv.x + r0b.w*wv.y + r1b.z*wv.z + r1b.w*wv.w;
  }
  float* op = out + ((size_t)(b*128 + o))*NN + i*96 + j0;
  *(float4*)op = make_float4(a0,a1,a2,a3);
}

/* ---- 1x1 conv 128->64: out[b][cc][n] = sum_c W[cc][c]*X[b][c][n] ---- */
__global__ __launch_bounds__(256) void k_conv(const float* __restrict__ X,
    const float* __restrict__ WG, float* __restrict__ out)
{
  __shared__ __align__(16) float Xs[128*32];   /* [c][32 n] 16KB */
  __shared__ __align__(16) float wt[128*64];   /* [c][cc]   32KB */
  int b  = blockIdx.x / 288;
  int n0 = (blockIdx.x % 288) * 32;
  int t  = threadIdx.x;
  for (int idx = t; idx < 8192; idx += 256) {
    int c = idx >> 6, cc = idx & 63;
    wt[idx] = WG[cc*128 + c];
  }
  for (int idx = t; idx < 1024; idx += 256) {  /* 128 rows x 8 float4 */
    int c = idx >> 3, wq = idx & 7;
    ((float4*)Xs)[idx] = *(const float4*)&X[((size_t)(b*128 + c))*NN + n0 + wq*4];
  }
  __syncthreads();
  int n = t & 31, og = t >> 5;      /* og 0..7 -> cc = og*8+k */
  float acc[8];
  #pragma unroll
  for (int k = 0; k < 8; k++) acc[k] = 0.f;
  for (int c = 0; c < 128; c++) {
    float xv = Xs[(c<<5) + n];
    const float* wrow = wt + (c<<6) + og*8;
    float4 wa = *(const float4*)wrow;
    float4 wb = *(const float4*)(wrow + 4);
    acc[0]+=wa.x*xv; acc[1]+=wa.y*xv; acc[2]+=wa.z*xv; acc[3]+=wa.w*xv;
    acc[4]+=wb.x*xv; acc[5]+=wb.y*xv; acc[6]+=wb.z*xv; acc[7]+=wb.w*xv;
  }
  #pragma unroll
  for (int k = 0; k < 8; k++)
    out[((size_t)(b*64 + og*8 + k))*NN + n0 + n] = acc[k];
}

/* ---- 2x2 maxpool f32 [b][64][96][96] -> [b][64][48][48] ---- */
__global__ __launch_bounds__(256) void k_pool(const float* __restrict__ in, float* __restrict__ out)
{
  int t = blockIdx.x*256 + threadIdx.x;   /* 589824 */
  int J = t % 48; int r = t/48; int I = r % 48; r /= 48; int cc = r & 63; int b = r >> 6;
  const float* p = in + ((size_t)(b*64+cc))*NN + (size_t)(2*I)*96 + 2*J;
  float m = fmaxf(fmaxf(p[0],p[1]), fmaxf(p[96],p[97]));
  out[((size_t)(b*64+cc))*MM + I*48 + J] = m;
}

/* ---- MFMA flash attention (bf16 inputs, f32 accum).
   Block: 64 queries (4 waves x 16), keys chunked by 64.
   LDS u16 map:  phi_T [k 64][72]  @0      (9216 B)
                 g_l   [cc 64][72] @4608   (9216 B)
                 P_l   per wave [16 q][72] @9216+wv*1152
   epilogue reuses LDS as f32 [wave][64 cc][20] for coalesced O store. ---- */
__global__ __launch_bounds__(256) void k_attn(const float* __restrict__ TH,
    const float* __restrict__ PH, const float* __restrict__ G, float* __restrict__ OUT)
{
  __shared__ __align__(16) u16 sm[13824];   /* 27648 B */
  int t = threadIdx.x;
  int lane = t & 63, wv = t >> 6;
  int quad = lane >> 4, l15 = lane & 15;
  int b  = blockIdx.x / 144;
  int q0 = (blockIdx.x % 144) * 64;
  int qw = q0 + wv*16;

  /* theta A-fragments, TEMP pre-scaled: A[q=l15][c=half*32+quad*8+j] */
  bf16x8 afrag[2];
  #pragma unroll
  for (int h = 0; h < 2; h++)
    #pragma unroll
    for (int j = 0; j < 8; j++) {
      float v = TEMPF * TH[((size_t)(b*64 + h*32 + quad*8 + j))*NN + qw + l15];
      afrag[h][j] = (short)f2bf(v);
    }

  f32x4 oacc[4];
  #pragma unroll
  for (int ct = 0; ct < 4; ct++)
    #pragma unroll
    for (int r = 0; r < 4; r++) oacc[ct][r] = 0.f;
  float m_r[4], l_r[4];
  #pragma unroll
  for (int r = 0; r < 4; r++) { m_r[r] = -3.0e38f; l_r[r] = 0.f; }

  int kth = t & 63;          /* staging: k lane */
  int cg  = t >> 6;

  for (int k0 = 0; k0 < MM; k0 += 64) {
    __syncthreads();                       /* prev PV done before overwrite */
    /* stage phi_T[k][c] (transpose f32->bf16) */
    #pragma unroll
    for (int h = 0; h < 2; h++) {
      int c0 = cg*16 + h*8;
      u32 pk[4];
      #pragma unroll
      for (int p = 0; p < 4; p++) {
        float f0 = PH[((size_t)(b*64 + c0 + 2*p    ))*MM + k0 + kth];
        float f1 = PH[((size_t)(b*64 + c0 + 2*p + 1))*MM + k0 + kth];
        pk[p] = pkbf(f0, f1);
      }
      *(uint4*)&sm[kth*72 + c0] = make_uint4(pk[0],pk[1],pk[2],pk[3]);
    }
    /* stage g_l[cc][k] (same layout as global) */
    {
      int cc = t >> 2, kq = (t & 3) << 4;
      const float* gp = &G[((size_t)(b*64 + cc))*MM + k0 + kq];
      u32 w[8];
      #pragma unroll
      for (int p = 0; p < 8; p++) w[p] = pkbf(gp[2*p], gp[2*p+1]);
      *(uint4*)&sm[4608 + cc*72 + kq]     = make_uint4(w[0],w[1],w[2],w[3]);
      *(uint4*)&sm[4608 + cc*72 + kq + 8] = make_uint4(w[4],w[5],w[6],w[7]);
    }
    __syncthreads();

    /* QK^T: 4 key-tiles x (2 MFMA over c) -> S[q=quad*4+r][key=kt*16+l15] */
    f32x4 s[4];
    #pragma unroll
    for (int kt = 0; kt < 4; kt++) {
      f32x4 acc;
      #pragma unroll
      for (int r = 0; r < 4; r++) acc[r] = 0.f;
      #pragma unroll
      for (int h = 0; h < 2; h++) {
        bf16x8 bfrag = *(const bf16x8*)&sm[(kt*16 + l15)*72 + h*32 + quad*8];
        acc = __builtin_amdgcn_mfma_f32_16x16x32_bf16(afrag[h], bfrag, acc, 0, 0, 0);
      }
      s[kt] = acc;
    }

    /* online softmax, per row r (q = quad*4+r), reduce over 16 lanes + 4 tiles */
    float al[4];
    #pragma unroll
    for (int r = 0; r < 4; r++) {
      float mx = fmaxf(fmaxf(s[0][r], s[1][r]), fmaxf(s[2][r], s[3][r]));
      #pragma unroll
      for (int d = 1; d < 16; d <<= 1) mx = fmaxf(mx, __shfl_xor(mx, d));
      float mn = fmaxf(m_r[r], mx);
      float a  = __expf(m_r[r] - mn);
      m_r[r] = mn;
      float ps = 0.f;
      #pragma unroll
      for (int kt = 0; kt < 4; kt++) {
        float p = __expf(s[kt][r] - mn);
        s[kt][r] = p; ps += p;
      }
      #pragma unroll
      for (int d = 1; d < 16; d <<= 1) ps += __shfl_xor(ps, d);
      l_r[r] = l_r[r]*a + ps;
      al[r] = a;
    }
    /* P -> per-wave LDS (bf16), rescale O */
    #pragma unroll
    for (int kt = 0; kt < 4; kt++)
      #pragma unroll
      for (int r = 0; r < 4; r++)
        sm[9216 + wv*1152 + (quad*4 + r)*72 + kt*16 + l15] = f2bf(s[kt][r]);
    #pragma unroll
    for (int ct = 0; ct < 4; ct++)
      #pragma unroll
      for (int r = 0; r < 4; r++) oacc[ct][r] *= al[r];

    /* PV: A = P[q=l15][key=h*32+quad*8+j], B = g[key][cc=ct*16+l15] */
    bf16x8 pf[2];
    #pragma unroll
    for (int h = 0; h < 2; h++)
      pf[h] = *(const bf16x8*)&sm[9216 + wv*1152 + l15*72 + h*32 + quad*8];
    #pragma unroll
    for (int ct = 0; ct < 4; ct++)
      #pragma unroll
      for (int h = 0; h < 2; h++) {
        bf16x8 gf = *(const bf16x8*)&sm[4608 + (ct*16 + l15)*72 + h*32 + quad*8];
        oacc[ct] = __builtin_amdgcn_mfma_f32_16x16x32_bf16(pf[h], gf, oacc[ct], 0, 0, 0);
      }
  }

  __syncthreads();   /* all waves done with phi/g/P regions */
  /* normalize + transpose through LDS for coalesced store */
  float inv[4];
  #pragma unroll
  for (int r = 0; r < 4; r++) inv[r] = 1.0f / l_r[r];
  float* ol = (float*)sm + wv*1280;      /* [cc 64][20] */
  #pragma unroll
  for (int ct = 0; ct < 4; ct++)
    #pragma unroll
    for (int r = 0; r < 4; r++)
      ol[(ct*16 + l15)*20 + quad*4 + r] = oacc[ct][r] * inv[r];
  __syncthreads();
  const float* orow = ol + lane*20;      /* cc = lane */
  float4 v0 = *(const float4*)(orow);
  float4 v1 = *(const float4*)(orow + 4);
  float4 v2 = *(const float4*)(orow + 8);
  float4 v3 = *(const float4*)(orow + 12);
  float* dst = &OUT[((size_t)(b*64 + lane))*NN + qw];
  *(float4*)(dst)      = v0;
  *(float4*)(dst + 4)  = v1;
  *(float4*)(dst + 8)  = v2;
  *(float4*)(dst + 12) = v3;
}

/* ---- o-projection 64->128, swizzled store into k_up block-own prefixes:
   ofin[b][o][i][j] -> dout[b slab][plane o>>2][2i+((o>>1)&1)][2j+(o&1)] ---- */
__global__ __launch_bounds__(256) void k_oconv(const float* __restrict__ X,
    const float* __restrict__ OW, float* __restrict__ dout)
{
  __shared__ __align__(16) float Xs[64*64];    /* [cc][64 n] 16KB */
  __shared__ __align__(16) float wt[64*128];   /* [cc][o]    32KB */
  int b  = blockIdx.x / 144;
  int n0 = (blockIdx.x % 144) * 64;
  int t  = threadIdx.x;
  for (int idx = t; idx < 8192; idx += 256) {
    int cc = idx >> 7, o = idx & 127;
    wt[idx] = OW[o*64 + cc];
  }
  for (int idx = t; idx < 1024; idx += 256) {  /* 64 rows x 16 float4 */
    int cc = idx >> 4, wq = idx & 15;
    ((float4*)Xs)[idx] = *(const float4*)&X[((size_t)(b*64 + cc))*NN + n0 + wq*4];
  }
  __syncthreads();
  int n = t & 63, og = t >> 6;       /* og 0..3 -> o = og*32+k */
  float acc[32];
  #pragma unroll
  for (int k = 0; k < 32; k++) acc[k] = 0.f;
  for (int cc = 0; cc < 64; cc++) {
    float xv = Xs[(cc << 6) + n];
    const float* wrow = wt + (cc << 7) + og*32;
    #pragma unroll
    for (int k = 0; k < 32; k++) acc[k] += wrow[k]*xv;
  }
  int ng = n0 + n;
  int i = ng / 96, j = ng - (ng/96)*96;
  #pragma unroll
  for (int k = 0; k < 32; k++) {
    int o = og*32 + k;
    size_t addr = (size_t)b*SLABF + (size_t)(o>>2)*HW
                + (size_t)(2*i + ((o>>1)&1))*192 + 2*j + (o&1);
    dout[addr] = acc[k];
  }
}

/* ---- up convtranspose + bias + gamma*y, f32, in-place over d_out. ---- */
__global__ __launch_bounds__(256) void k_up(float* __restrict__ dout,
    const float* __restrict__ upw, const float* __restrict__ upb,
    const float* __restrict__ Y, const float* __restrict__ gamma_p)
{
  __shared__ __align__(16) float o_s[128*96];   /* [c][j] 48KB */
  int blk = blockIdx.x;
  int b = blk / 96, i = blk - b*96;
  int t = threadIdx.x;
  size_t slab = (size_t)b*SLABF;
  const float* src = dout + slab + (size_t)(2*i)*192;

  /* phase 0: unswizzle own prefix -> LDS */
  for (int idx = t; idx < 12288; idx += 256) {   /* 32 planes x 2 rows x 192 */
    int run = idx / 384, rem = idx - run*384;
    int r = rem / 192, col = rem - r*192;
    float v = src[(size_t)run*HW + r*192 + col];
    int o = 4*run + 2*r + (col&1);
    o_s[o*96 + (col>>1)] = v;
  }
  __syncthreads();

  int op5 = t >> 3, jg = t & 7;
  float gm = *gamma_p;

  for (int opc = 0; opc < 4; opc++) {
    int op = opc*32 + op5;
    float bias = upb[op];
    size_t obase = slab + (size_t)op*HW + (size_t)(2*i)*192;
    for (int s = 0; s < 3; s++) {
      int j0 = jg*12 + s*4;
      float a00[4], a01[4], a10[4], a11[4];
      #pragma unroll
      for (int jj = 0; jj < 4; jj++) { a00[jj]=0.f; a01[jj]=0.f; a10[jj]=0.f; a11[jj]=0.f; }
      for (int c = 0; c < 128; c++) {
        float4 ov = *(const float4*)&o_s[c*96 + j0];
        float4 wv = *(const float4*)&upw[((size_t)c*128 + op)*4];  /* w00 w01 w10 w11 */
        a00[0]+=ov.x*wv.x; a01[0]+=ov.x*wv.y; a10[0]+=ov.x*wv.z; a11[0]+=ov.x*wv.w;
        a00[1]+=ov.y*wv.x; a01[1]+=ov.y*wv.y; a10[1]+=ov.y*wv.z; a11[1]+=ov.y*wv.w;
        a00[2]+=ov.z*wv.x; a01[2]+=ov.z*wv.y; a10[2]+=ov.z*wv.z; a11[2]+=ov.z*wv.w;
        a00[3]+=ov.w*wv.x; a01[3]+=ov.w*wv.y; a10[3]+=ov.w*wv.z; a11[3]+=ov.w*wv.w;
      }
      size_t p0 = obase + 2*j0;          /* row 2i,  col 2*j0 */
      size_t p1 = p0 + 192;              /* row 2i+1 */
      float4 y0a = *(const float4*)&Y[p0];
      float4 y0b = *(const float4*)&Y[p0 + 4];
      float4 y1a = *(const float4*)&Y[p1];
      float4 y1b = *(const float4*)&Y[p1 + 4];
      *(float4*)&dout[p0]     = make_float4(a00[0]+bias+gm*y0a.x, a01[0]+bias+gm*y0a.y,
                                            a00[1]+bias+gm*y0a.z, a01[1]+bias+gm*y0a.w);
      *(float4*)&dout[p0 + 4] = make_float4(a00[2]+bias+gm*y0b.x, a01[2]+bias+gm*y0b.y,
                                            a00[3]+bias+gm*y0b.z, a01[3]+bias+gm*y0b.w);
      *(float4*)&dout[p1]     = make_float4(a10[0]+bias+gm*y1a.x, a11[0]+bias+gm*y1a.y,
                                            a10[1]+bias+gm*y1a.z, a11[1]+bias+gm*y1a.w);
      *(float4*)&dout[p1 + 4] = make_float4(a10[2]+bias+gm*y1b.x, a11[2]+bias+gm*y1b.y,
                                            a10[3]+bias+gm*y1b.z, a11[3]+bias+gm*y1b.w);
    }
  }
}

extern "C" void kernel_launch(void* const* d_in, const int* in_sizes, int n_in,
                              void* d_out, int out_size, void* d_ws, size_t ws_size,
                              hipStream_t stream) {
  const float* x_in  = (const float*)d_in[0];
  const float* y_in  = (const float*)d_in[1];
  const float* d0w   = (const float*)d_in[2];
  const float* d0b   = (const float*)d_in[3];
  const float* d1w   = (const float*)d_in[4];
  const float* d1b   = (const float*)d_in[5];
  const float* thw   = (const float*)d_in[6];
  const float* phw   = (const float*)d_in[7];
  const float* gw    = (const float*)d_in[8];
  const float* ow    = (const float*)d_in[9];
  const float* upw   = (const float*)d_in[10];
  const float* upb   = (const float*)d_in[11];
  const float* gamma = (const float*)d_in[12];
  float* out = (float*)d_out;

  /* d_ws UNUSED; d_in READ-ONLY; all scratch in d_out (see offset map). */
  k_down <<<4608, 256, 0, stream>>>(x_in, d0w, d0b, out + OFF_X);
  k_down <<<4608, 256, 0, stream>>>(y_in, d1w, d1b, out + OFF_Y);
  k_conv <<<1152, 256, 0, stream>>>(out + OFF_X, thw, out + OFF_TH);
  k_conv <<<1152, 256, 0, stream>>>(out + OFF_X, phw, out + OFF_TP);
  k_pool <<<2304, 256, 0, stream>>>(out + OFF_TP, out + OFF_PH);
  k_conv <<<1152, 256, 0, stream>>>(out + OFF_Y, gw, out + OFF_TP);
  k_pool <<<2304, 256, 0, stream>>>(out + OFF_TP, out + OFF_G);
  k_attn <<<576,  256, 0, stream>>>(out + OFF_TH, out + OFF_PH, out + OFF_G, out + OFF_OM);
  k_oconv<<<576,  256, 0, stream>>>(out + OFF_OM, ow, out);
  k_up   <<<384,  256, 0, stream>>>(out, upw, upb, y_in, gamma);
}